// Round 1
// baseline (552.611 us; speedup 1.0000x reference)
//
#include <hip/hip_runtime.h>
#include <stdint.h>

// SAGEConv: out = concat([x, mean_neigh(x)]) @ W.T + b
// N=100000, MAX_DEG=16, D_IN=256, D_OUT=256 (N % 32 == 0, no tail handling)

#define MAX_DEG 16
#define D_IN 256
#define D_K 512
#define D_OUT 256
#define BM 32
#define LDS_STRIDE 520   // 512 + 8 bf16 pad (16B) keeps b128 reads conflict-floor

typedef __attribute__((ext_vector_type(8))) short bf16x8;   // 8 bf16 = 4 VGPRs
typedef __attribute__((ext_vector_type(4))) float f32x4;

__device__ __forceinline__ ushort f2bf(float f) {
    union { float f; uint32_t u; } v; v.f = f;
    uint32_t u = v.u;
    uint32_t r = (u + 0x7FFFu + ((u >> 16) & 1u)) >> 16;   // RNE; inputs finite
    return (ushort)r;
}

__global__ __launch_bounds__(256) void cast_w_kernel(const float* __restrict__ W,
                                                     ushort* __restrict__ Wb) {
    int i = (blockIdx.x * 256 + threadIdx.x) * 4;
    float4 v = *(const float4*)(W + i);
    ushort4 p = { f2bf(v.x), f2bf(v.y), f2bf(v.z), f2bf(v.w) };
    *(ushort4*)(Wb + i) = p;
}

__global__ __launch_bounds__(256) void sage_fused_kernel(
    const float* __restrict__ x,
    const int* __restrict__ edge,
    const ushort* __restrict__ Wb,     // bf16 bits, [D_OUT][D_K] row-major
    const float* __restrict__ bias,
    float* __restrict__ out,
    int n_nodes)
{
    __shared__ ushort sH[BM * LDS_STRIDE];   // 33,280 B

    const int tid = threadIdx.x;
    const int node0 = blockIdx.x * BM;

    // ---------- Phase 1: build bf16 H-tile = [x | mean_neigh] ----------
    {
        const int m = tid >> 3;          // node within tile, 0..31
        const int l = tid & 7;           // 32-column chunk, 0..7
        const int node = node0 + m;

        // x half
        const float4* xrow = (const float4*)(x + (size_t)node * D_IN);
        float4 v[8];
        #pragma unroll
        for (int q = 0; q < 8; ++q) v[q] = xrow[l * 8 + q];
        ushort* dst = sH + m * LDS_STRIDE + l * 32;
        #pragma unroll
        for (int q = 0; q < 8; ++q) {
            ushort4 p = { f2bf(v[q].x), f2bf(v[q].y), f2bf(v[q].z), f2bf(v[q].w) };
            *(ushort4*)(dst + q * 4) = p;
        }

        // mean aggregation (fp32 accumulate)
        float4 agg[8];
        #pragma unroll
        for (int q = 0; q < 8; ++q) agg[q] = make_float4(0.f, 0.f, 0.f, 0.f);
        int deg = 0;
        for (int d = 0; d < MAX_DEG; ++d) {
            int nb = edge[(size_t)node * MAX_DEG + d];
            if (nb >= 0) {
                ++deg;
                const float4* nr = (const float4*)(x + (size_t)nb * D_IN);
                #pragma unroll
                for (int q = 0; q < 8; ++q) {
                    float4 t = nr[l * 8 + q];
                    agg[q].x += t.x; agg[q].y += t.y;
                    agg[q].z += t.z; agg[q].w += t.w;
                }
            }
        }
        const float inv = 1.0f / (float)deg;   // deg >= 1 (col 0 always valid)
        ushort* dst2 = sH + m * LDS_STRIDE + D_IN + l * 32;
        #pragma unroll
        for (int q = 0; q < 8; ++q) {
            ushort4 p = { f2bf(agg[q].x * inv), f2bf(agg[q].y * inv),
                          f2bf(agg[q].z * inv), f2bf(agg[q].w * inv) };
            *(ushort4*)(dst2 + q * 4) = p;
        }
    }
    __syncthreads();

    // ---------- Phase 2: out[32,256] = H @ W^T + b via 16x16x32 bf16 MFMA ----------
    {
        const int wave = tid >> 6;
        const int lane = tid & 63;
        const int quad = lane >> 4;
        const int r16  = lane & 15;
        const int mt = wave & 1;     // 16-row strip of the 32-node tile
        const int nh = wave >> 1;    // 128-col half of the 256 outputs

        f32x4 acc[8];
        #pragma unroll
        for (int j = 0; j < 8; ++j) {
            float bv = bias[(nh * 8 + j) * 16 + r16];   // D col = lane&15
            acc[j] = (f32x4){bv, bv, bv, bv};           // bias as initial C
        }

        // A-frag: A[m=lane&15][k=quad*8+j] -> 16B contiguous along k
        const ushort* arow = sH + (mt * 16 + r16) * LDS_STRIDE + quad * 8;
        #pragma unroll
        for (int ks = 0; ks < D_K / 32; ++ks) {
            bf16x8 a = *(const bf16x8*)(arow + ks * 32);
            #pragma unroll
            for (int j = 0; j < 8; ++j) {
                const int o = (nh * 8 + j) * 16 + r16;  // B: n = lane&15
                bf16x8 b = *(const bf16x8*)(Wb + (size_t)o * D_K + ks * 32 + quad * 8);
                acc[j] = __builtin_amdgcn_mfma_f32_16x16x32_bf16(a, b, acc[j], 0, 0, 0);
            }
        }

        // D layout: col = lane&15, row = quad*4 + reg
        #pragma unroll
        for (int j = 0; j < 8; ++j) {
            const int o = (nh * 8 + j) * 16 + r16;
            #pragma unroll
            for (int r = 0; r < 4; ++r) {
                const int row = node0 + mt * 16 + quad * 4 + r;
                out[(size_t)row * D_OUT + o] = acc[j][r];
            }
        }
    }
}

extern "C" void kernel_launch(void* const* d_in, const int* in_sizes, int n_in,
                              void* d_out, int out_size, void* d_ws, size_t ws_size,
                              hipStream_t stream) {
    const float* x    = (const float*)d_in[0];
    const int*   edge = (const int*)d_in[1];
    const float* W    = (const float*)d_in[2];
    const float* bias = (const float*)d_in[3];
    float* out = (float*)d_out;
    ushort* Wb = (ushort*)d_ws;            // 256 KB bf16 W copy

    const int n = in_sizes[0] / D_IN;      // 100000
    const int welems = in_sizes[2];        // 131072

    cast_w_kernel<<<welems / 1024, 256, 0, stream>>>(W, Wb);
    sage_fused_kernel<<<n / BM, 256, 0, stream>>>(x, edge, Wb, bias, out, n);
}

// Round 2
// 418.742 us; speedup vs baseline: 1.3197x; 1.3197x over previous
//
#include <hip/hip_runtime.h>
#include <stdint.h>

// SAGEConv: out = concat([x, mean_neigh(x)]) @ W.T + b
// N=100000, MAX_DEG=16, D_IN=256, D_OUT=256
//
// Strategy: pre-cast x and W to bf16 in d_ws (x gets a zero row at index N so
// padding edges gather zeros unconditionally). Fused kernel: BM=16 nodes/block,
// phase 1 gathers bf16 rows (fp32 accumulate) into a bf16 LDS H-tile, phase 2
// does H @ W^T via 16x16x32 bf16 MFMA with B-frags read straight from L2.

#define MAX_DEG 16
#define D_IN 256
#define D_K 512
#define D_OUT 256
#define BM 16
#define LDS_STRIDE 520   // 512 + 8 bf16 pad; keeps rows 16B-aligned
#define N_NODES_C 100000

typedef __attribute__((ext_vector_type(8))) short bf16x8;   // 8 bf16 = 4 VGPRs
typedef __attribute__((ext_vector_type(4))) float f32x4;

__device__ __forceinline__ uint32_t f2bf(float f) {
    union { float f; uint32_t u; } v; v.f = f;
    uint32_t u = v.u;
    return (u + 0x7FFFu + ((u >> 16) & 1u)) >> 16;   // RNE; inputs finite
}
__device__ __forceinline__ uint32_t pack2(float lo, float hi) {
    return f2bf(lo) | (f2bf(hi) << 16);
}

// ---- one kernel casts x (+ zero row) and W to bf16 in ws ----
// blocks [0,12500): x | block 12500: zero row | blocks [12501,12565): W
__global__ __launch_bounds__(256) void cast_all_kernel(
    const float* __restrict__ x, const float* __restrict__ W,
    ushort* __restrict__ Xb, ushort* __restrict__ Wb)
{
    const int b = blockIdx.x;
    const int tid = threadIdx.x;
    if (b < 12500) {
        const size_t i = (size_t)b * 2048 + tid * 8;
        float4 v0 = *(const float4*)(x + i);
        float4 v1 = *(const float4*)(x + i + 4);
        uint4 p = { pack2(v0.x, v0.y), pack2(v0.z, v0.w),
                    pack2(v1.x, v1.y), pack2(v1.z, v1.w) };
        *(uint4*)(Xb + i) = p;
    } else if (b == 12500) {
        if (tid < 32) {
            uint4 z = {0u, 0u, 0u, 0u};
            *(uint4*)(Xb + (size_t)N_NODES_C * D_IN + tid * 8) = z;
        }
    } else {
        const size_t i = (size_t)(b - 12501) * 2048 + tid * 8;
        float4 v0 = *(const float4*)(W + i);
        float4 v1 = *(const float4*)(W + i + 4);
        uint4 p = { pack2(v0.x, v0.y), pack2(v0.z, v0.w),
                    pack2(v1.x, v1.y), pack2(v1.z, v1.w) };
        *(uint4*)(Wb + i) = p;
    }
}

__global__ __launch_bounds__(256, 6) void sage_bf16_kernel(
    const ushort* __restrict__ Xb,     // [N_NODES+1][D_IN] bf16, row N = zeros
    const int* __restrict__ edge,
    const ushort* __restrict__ Wb,     // [D_OUT][D_K] bf16
    const float* __restrict__ bias,
    float* __restrict__ out)
{
    __shared__ ushort sH[BM * LDS_STRIDE];   // 16,640 B

    const int tid = threadIdx.x;
    const int node0 = blockIdx.x * BM;

    // ---------- Phase 1: H-tile = [x | mean_neigh], bf16 in LDS ----------
    {
        const int m = tid >> 4;          // node in tile, 0..15
        const int l = tid & 15;          // 16-col chunk, 0..15
        const int node = node0 + m;

        // self half: bf16 copy straight to LDS
        const uint4* xr = (const uint4*)(Xb + (size_t)node * D_IN + l * 16);
        uint4 s0 = xr[0], s1 = xr[1];
        uint4* dst = (uint4*)(sH + m * LDS_STRIDE + l * 16);
        dst[0] = s0; dst[1] = s1;

        // edges: clamp pad (-1) to the zero row, count degree
        const int4* ep = (const int4*)(edge + (size_t)node * MAX_DEG);
        int idx[16]; int deg = 0;
        #pragma unroll
        for (int g = 0; g < 4; ++g) {
            int4 e = ep[g];
            int v0 = e.x, v1 = e.y, v2 = e.z, v3 = e.w;
            deg += (v0 >= 0) + (v1 >= 0) + (v2 >= 0) + (v3 >= 0);
            idx[g*4+0] = v0 < 0 ? N_NODES_C : v0;
            idx[g*4+1] = v1 < 0 ? N_NODES_C : v1;
            idx[g*4+2] = v2 < 0 ? N_NODES_C : v2;
            idx[g*4+3] = v3 < 0 ? N_NODES_C : v3;
        }

        float c[16];
        #pragma unroll
        for (int q = 0; q < 16; ++q) c[q] = 0.f;

        #pragma unroll 4
        for (int d = 0; d < MAX_DEG; ++d) {
            const uint4* nr = (const uint4*)(Xb + (size_t)idx[d] * D_IN + l * 16);
            uint4 a0 = nr[0], a1 = nr[1];
            uint32_t u[8] = {a0.x, a0.y, a0.z, a0.w, a1.x, a1.y, a1.z, a1.w};
            #pragma unroll
            for (int q = 0; q < 8; ++q) {
                union { uint32_t ui; float f; } lo, hi;
                lo.ui = u[q] << 16;
                hi.ui = u[q] & 0xFFFF0000u;
                c[2*q]   += lo.f;
                c[2*q+1] += hi.f;
            }
        }

        const float inv = 1.0f / (float)deg;   // deg >= 1
        uint4 p0 = { pack2(c[0]*inv,  c[1]*inv),  pack2(c[2]*inv,  c[3]*inv),
                     pack2(c[4]*inv,  c[5]*inv),  pack2(c[6]*inv,  c[7]*inv) };
        uint4 p1 = { pack2(c[8]*inv,  c[9]*inv),  pack2(c[10]*inv, c[11]*inv),
                     pack2(c[12]*inv, c[13]*inv), pack2(c[14]*inv, c[15]*inv) };
        uint4* dst2 = (uint4*)(sH + m * LDS_STRIDE + D_IN + l * 16);
        dst2[0] = p0; dst2[1] = p1;
    }
    __syncthreads();

    // ---------- Phase 2: out[16,256] = H @ W^T + b, 16x16x32 bf16 MFMA ----------
    {
        const int wave = tid >> 6;       // col quarter (64 cols)
        const int lane = tid & 63;
        const int quad = lane >> 4;
        const int r16  = lane & 15;

        f32x4 acc[4];
        #pragma unroll
        for (int j = 0; j < 4; ++j) {
            float bv = bias[wave * 64 + j * 16 + r16];   // D col = lane&15
            acc[j] = (f32x4){bv, bv, bv, bv};
        }

        const ushort* arow = sH + r16 * LDS_STRIDE + quad * 8;  // A[m][k]=quad*8+j
        #pragma unroll
        for (int ks = 0; ks < D_K / 32; ++ks) {
            bf16x8 a = *(const bf16x8*)(arow + ks * 32);
            #pragma unroll
            for (int j = 0; j < 4; ++j) {
                const int o = wave * 64 + j * 16 + r16;          // B: n = lane&15
                bf16x8 b = *(const bf16x8*)(Wb + (size_t)o * D_K + ks * 32 + quad * 8);
                acc[j] = __builtin_amdgcn_mfma_f32_16x16x32_bf16(a, b, acc[j], 0, 0, 0);
            }
        }

        // D layout: col = lane&15, row = quad*4 + reg
        #pragma unroll
        for (int j = 0; j < 4; ++j) {
            const int o = wave * 64 + j * 16 + r16;
            #pragma unroll
            for (int r = 0; r < 4; ++r) {
                const int row = node0 + quad * 4 + r;
                out[(size_t)row * D_OUT + o] = acc[j][r];
            }
        }
    }
}

// ---------------- fallback (small ws): round-1 fp32-gather path ----------------
__global__ __launch_bounds__(256) void cast_w_kernel(const float* __restrict__ W,
                                                     ushort* __restrict__ Wb) {
    int i = (blockIdx.x * 256 + threadIdx.x) * 4;
    float4 v = *(const float4*)(W + i);
    ushort4 p = { (ushort)f2bf(v.x), (ushort)f2bf(v.y),
                  (ushort)f2bf(v.z), (ushort)f2bf(v.w) };
    *(ushort4*)(Wb + i) = p;
}

__global__ __launch_bounds__(256) void sage_fp32_kernel(
    const float* __restrict__ x, const int* __restrict__ edge,
    const ushort* __restrict__ Wb, const float* __restrict__ bias,
    float* __restrict__ out)
{
    __shared__ ushort sH[32 * LDS_STRIDE];
    const int tid = threadIdx.x;
    const int node0 = blockIdx.x * 32;
    {
        const int m = tid >> 3, l = tid & 7;
        const int node = node0 + m;
        const float4* xrow = (const float4*)(x + (size_t)node * D_IN);
        ushort* dst = sH + m * LDS_STRIDE + l * 32;
        #pragma unroll
        for (int q = 0; q < 8; ++q) {
            float4 v = xrow[l * 8 + q];
            ushort4 p = { (ushort)f2bf(v.x), (ushort)f2bf(v.y),
                          (ushort)f2bf(v.z), (ushort)f2bf(v.w) };
            *(ushort4*)(dst + q * 4) = p;
        }
        float4 agg[8];
        #pragma unroll
        for (int q = 0; q < 8; ++q) agg[q] = make_float4(0.f,0.f,0.f,0.f);
        int deg = 0;
        for (int d = 0; d < MAX_DEG; ++d) {
            int nb = edge[(size_t)node * MAX_DEG + d];
            if (nb >= 0) {
                ++deg;
                const float4* nr = (const float4*)(x + (size_t)nb * D_IN);
                #pragma unroll
                for (int q = 0; q < 8; ++q) {
                    float4 t = nr[l * 8 + q];
                    agg[q].x += t.x; agg[q].y += t.y;
                    agg[q].z += t.z; agg[q].w += t.w;
                }
            }
        }
        const float inv = 1.0f / (float)deg;
        ushort* dst2 = sH + m * LDS_STRIDE + D_IN + l * 32;
        #pragma unroll
        for (int q = 0; q < 8; ++q) {
            ushort4 p = { (ushort)f2bf(agg[q].x*inv), (ushort)f2bf(agg[q].y*inv),
                          (ushort)f2bf(agg[q].z*inv), (ushort)f2bf(agg[q].w*inv) };
            *(ushort4*)(dst2 + q * 4) = p;
        }
    }
    __syncthreads();
    {
        const int wave = tid >> 6, lane = tid & 63;
        const int quad = lane >> 4, r16 = lane & 15;
        const int mt = wave & 1, nh = wave >> 1;
        f32x4 acc[8];
        #pragma unroll
        for (int j = 0; j < 8; ++j) {
            float bv = bias[(nh * 8 + j) * 16 + r16];
            acc[j] = (f32x4){bv, bv, bv, bv};
        }
        const ushort* arow = sH + (mt * 16 + r16) * LDS_STRIDE + quad * 8;
        #pragma unroll
        for (int ks = 0; ks < D_K / 32; ++ks) {
            bf16x8 a = *(const bf16x8*)(arow + ks * 32);
            #pragma unroll
            for (int j = 0; j < 8; ++j) {
                const int o = (nh * 8 + j) * 16 + r16;
                bf16x8 b = *(const bf16x8*)(Wb + (size_t)o * D_K + ks * 32 + quad * 8);
                acc[j] = __builtin_amdgcn_mfma_f32_16x16x32_bf16(a, b, acc[j], 0, 0, 0);
            }
        }
        #pragma unroll
        for (int j = 0; j < 8; ++j) {
            const int o = (nh * 8 + j) * 16 + r16;
            #pragma unroll
            for (int r = 0; r < 4; ++r) {
                const int row = node0 + mt * 16 + quad * 4 + r;
                out[(size_t)row * D_OUT + o] = acc[j][r];
            }
        }
    }
}

extern "C" void kernel_launch(void* const* d_in, const int* in_sizes, int n_in,
                              void* d_out, int out_size, void* d_ws, size_t ws_size,
                              hipStream_t stream) {
    const float* x    = (const float*)d_in[0];
    const int*   edge = (const int*)d_in[1];
    const float* W    = (const float*)d_in[2];
    const float* bias = (const float*)d_in[3];
    float* out = (float*)d_out;

    const size_t xb_bytes = (size_t)(N_NODES_C + 1) * D_IN * 2;   // 51,200,512
    const size_t wb_bytes = (size_t)D_OUT * D_K * 2;              // 262,144
    const int n = in_sizes[0] / D_IN;                             // 100000

    if (ws_size >= xb_bytes + wb_bytes) {
        ushort* Xb = (ushort*)d_ws;
        ushort* Wb = (ushort*)((char*)d_ws + xb_bytes);
        cast_all_kernel<<<12565, 256, 0, stream>>>(x, W, Xb, Wb);
        sage_bf16_kernel<<<n / BM, 256, 0, stream>>>(Xb, edge, Wb, bias, out);
    } else {
        ushort* Wb = (ushort*)d_ws;     // 256 KB
        cast_w_kernel<<<(D_OUT * D_K) / 1024, 256, 0, stream>>>(W, Wb);
        sage_fp32_kernel<<<n / 32, 256, 0, stream>>>(x, edge, Wb, bias, out);
    }
}

// Round 3
// 364.843 us; speedup vs baseline: 1.5147x; 1.1477x over previous
//
#include <hip/hip_runtime.h>
#include <stdint.h>

// SAGEConv: out = concat([x, mean_neigh(x)]) @ W.T + b
// N=100000, MAX_DEG=16, D_IN=256, D_OUT=256
//
// R3: latency-bound gather -> deep MLP. Phase 1 stages 16 independent 16B
// gather loads per thread before consuming (was ~2 outstanding at VGPR=40).
// BM=32, 512 threads; phase 2 waves cover both 16-row strips per B-frag,
// halving W refetch from L2.

#define MAX_DEG 16
#define D_IN 256
#define D_K 512
#define D_OUT 256
#define BM 32
#define LDS_STRIDE 520   // bf16 elems: 512 + 8 pad; rows stay 16B-aligned
#define N_NODES_C 100000

typedef __attribute__((ext_vector_type(8))) short bf16x8;   // 8 bf16 = 4 VGPRs
typedef __attribute__((ext_vector_type(4))) float f32x4;

__device__ __forceinline__ uint32_t f2bf(float f) {
    union { float f; uint32_t u; } v; v.f = f;
    uint32_t u = v.u;
    return (u + 0x7FFFu + ((u >> 16) & 1u)) >> 16;   // RNE; inputs finite
}
__device__ __forceinline__ uint32_t pack2(float lo, float hi) {
    return f2bf(lo) | (f2bf(hi) << 16);
}

// ---- cast x (+ zero row at index N) and W to bf16 in ws ----
__global__ __launch_bounds__(256) void cast_all_kernel(
    const float* __restrict__ x, const float* __restrict__ W,
    ushort* __restrict__ Xb, ushort* __restrict__ Wb)
{
    const int b = blockIdx.x;
    const int tid = threadIdx.x;
    if (b < 12500) {
        const size_t i = (size_t)b * 2048 + tid * 8;
        float4 v0 = *(const float4*)(x + i);
        float4 v1 = *(const float4*)(x + i + 4);
        uint4 p = { pack2(v0.x, v0.y), pack2(v0.z, v0.w),
                    pack2(v1.x, v1.y), pack2(v1.z, v1.w) };
        *(uint4*)(Xb + i) = p;
    } else if (b == 12500) {
        if (tid < 32) {
            uint4 z = {0u, 0u, 0u, 0u};
            *(uint4*)(Xb + (size_t)N_NODES_C * D_IN + tid * 8) = z;
        }
    } else {
        const size_t i = (size_t)(b - 12501) * 2048 + tid * 8;
        float4 v0 = *(const float4*)(W + i);
        float4 v1 = *(const float4*)(W + i + 4);
        uint4 p = { pack2(v0.x, v0.y), pack2(v0.z, v0.w),
                    pack2(v1.x, v1.y), pack2(v1.z, v1.w) };
        *(uint4*)(Wb + i) = p;
    }
}

__global__ __launch_bounds__(512, 4) void sage_bf16_kernel(
    const ushort* __restrict__ Xb,     // [N+1][D_IN] bf16, row N = zeros
    const int* __restrict__ edge,
    const ushort* __restrict__ Wb,     // [D_OUT][D_K] bf16
    const float* __restrict__ bias,
    float* __restrict__ out)
{
    __shared__ ushort sH[BM * LDS_STRIDE];   // 33,280 B

    const int tid = threadIdx.x;
    const int node0 = blockIdx.x * BM;

    // ---------- Phase 1: H-tile = [x | mean_neigh], bf16 in LDS ----------
    {
        const int m = tid >> 4;          // node in tile, 0..31
        const int l = tid & 15;          // lane-within-node, 0..15
        const int node = node0 + m;

        // self half: straight bf16 copy (two 16B chunks per thread)
        const uint4* xr = (const uint4*)(Xb + (size_t)node * D_IN);
        uint4* selfdst = (uint4*)(sH + (size_t)m * LDS_STRIDE);
        uint4 s0 = xr[l], s1 = xr[16 + l];
        selfdst[l] = s0; selfdst[16 + l] = s1;

        // neighbor byte-offsets (pad -1 -> zero row), degree
        const int4* ep = (const int4*)(edge + (size_t)node * MAX_DEG);
        uint32_t off[MAX_DEG]; int deg = 0;
        #pragma unroll
        for (int g = 0; g < 4; ++g) {
            int4 e = ep[g];
            deg += (e.x >= 0) + (e.y >= 0) + (e.z >= 0) + (e.w >= 0);
            off[g*4+0] = (uint32_t)(e.x < 0 ? N_NODES_C : e.x) * 512u;
            off[g*4+1] = (uint32_t)(e.y < 0 ? N_NODES_C : e.y) * 512u;
            off[g*4+2] = (uint32_t)(e.z < 0 ? N_NODES_C : e.z) * 512u;
            off[g*4+3] = (uint32_t)(e.w < 0 ? N_NODES_C : e.w) * 512u;
        }
        const float inv = 1.0f / (float)deg;   // deg >= 1
        const char* xb = (const char*)Xb;

        // chunk c covers row bytes [c*256, c*256+256); lane l owns 16B at +l*16
        // -> for fixed (d,c) the 16 lanes form one contiguous 256B burst
        #pragma unroll 1
        for (int c = 0; c < 2; ++c) {
            const uint32_t coff = (uint32_t)(c * 256 + l * 16);
            uint4 st[MAX_DEG];
            #pragma unroll
            for (int d = 0; d < MAX_DEG; ++d)
                st[d] = *(const uint4*)(xb + (size_t)(off[d] + coff));

            float a[8];
            #pragma unroll
            for (int q = 0; q < 8; ++q) a[q] = 0.f;
            #pragma unroll
            for (int d = 0; d < MAX_DEG; ++d) {
                uint32_t u[4] = { st[d].x, st[d].y, st[d].z, st[d].w };
                #pragma unroll
                for (int q = 0; q < 4; ++q) {
                    union { uint32_t ui; float f; } lo, hi;
                    lo.ui = u[q] << 16;
                    hi.ui = u[q] & 0xFFFF0000u;
                    a[2*q]   += lo.f;
                    a[2*q+1] += hi.f;
                }
            }
            uint4 p = { pack2(a[0]*inv, a[1]*inv), pack2(a[2]*inv, a[3]*inv),
                        pack2(a[4]*inv, a[5]*inv), pack2(a[6]*inv, a[7]*inv) };
            *(uint4*)(sH + (size_t)m * LDS_STRIDE + D_IN + c * 128 + l * 8) = p;
        }
    }
    __syncthreads();

    // ---------- Phase 2: out[32,256] = H @ W^T + b, 16x16x32 bf16 MFMA ----------
    // 8 waves; wave w = 32-col eighth, covers BOTH 16-row strips so each
    // B-frag load feeds 2 MFMAs (halves W L2 traffic).
    {
        const int w = tid >> 6;          // 0..7
        const int lane = tid & 63;
        const int quad = lane >> 4;
        const int r16  = lane & 15;

        f32x4 acc[2][2];
        #pragma unroll
        for (int j = 0; j < 2; ++j) {
            float bv = bias[w * 32 + j * 16 + r16];   // D col = lane&15
            acc[0][j] = (f32x4){bv, bv, bv, bv};
            acc[1][j] = (f32x4){bv, bv, bv, bv};
        }

        const ushort* a0p = sH + (size_t)r16 * LDS_STRIDE + quad * 8;  // strip 0
        const ushort* a1p = a0p + 16 * LDS_STRIDE;                     // strip 1
        #pragma unroll
        for (int ks = 0; ks < D_K / 32; ++ks) {
            bf16x8 a0 = *(const bf16x8*)(a0p + ks * 32);
            bf16x8 a1 = *(const bf16x8*)(a1p + ks * 32);
            #pragma unroll
            for (int j = 0; j < 2; ++j) {
                const int o = w * 32 + j * 16 + r16;                   // B: n = lane&15
                bf16x8 b = *(const bf16x8*)(Wb + (size_t)o * D_K + ks * 32 + quad * 8);
                acc[0][j] = __builtin_amdgcn_mfma_f32_16x16x32_bf16(a0, b, acc[0][j], 0, 0, 0);
                acc[1][j] = __builtin_amdgcn_mfma_f32_16x16x32_bf16(a1, b, acc[1][j], 0, 0, 0);
            }
        }

        // D layout: col = lane&15, row = quad*4 + reg
        #pragma unroll
        for (int mt = 0; mt < 2; ++mt) {
            #pragma unroll
            for (int j = 0; j < 2; ++j) {
                const int o = w * 32 + j * 16 + r16;
                #pragma unroll
                for (int r = 0; r < 4; ++r) {
                    const int row = node0 + mt * 16 + quad * 4 + r;
                    out[(size_t)row * D_OUT + o] = acc[mt][j][r];
                }
            }
        }
    }
}

// ---------------- fallback (small ws): fp32-gather path ----------------
__global__ __launch_bounds__(256) void cast_w_kernel(const float* __restrict__ W,
                                                     ushort* __restrict__ Wb) {
    int i = (blockIdx.x * 256 + threadIdx.x) * 4;
    float4 v = *(const float4*)(W + i);
    ushort4 p = { (ushort)f2bf(v.x), (ushort)f2bf(v.y),
                  (ushort)f2bf(v.z), (ushort)f2bf(v.w) };
    *(ushort4*)(Wb + i) = p;
}

__global__ __launch_bounds__(256) void sage_fp32_kernel(
    const float* __restrict__ x, const int* __restrict__ edge,
    const ushort* __restrict__ Wb, const float* __restrict__ bias,
    float* __restrict__ out)
{
    __shared__ ushort sH[32 * LDS_STRIDE];
    const int tid = threadIdx.x;
    const int node0 = blockIdx.x * 32;
    {
        const int m = tid >> 3, l = tid & 7;
        const int node = node0 + m;
        const float4* xrow = (const float4*)(x + (size_t)node * D_IN);
        ushort* dst = sH + m * LDS_STRIDE + l * 32;
        #pragma unroll
        for (int q = 0; q < 8; ++q) {
            float4 v = xrow[l * 8 + q];
            ushort4 p = { (ushort)f2bf(v.x), (ushort)f2bf(v.y),
                          (ushort)f2bf(v.z), (ushort)f2bf(v.w) };
            *(ushort4*)(dst + q * 4) = p;
        }
        float4 agg[8];
        #pragma unroll
        for (int q = 0; q < 8; ++q) agg[q] = make_float4(0.f,0.f,0.f,0.f);
        int deg = 0;
        for (int d = 0; d < MAX_DEG; ++d) {
            int nb = edge[(size_t)node * MAX_DEG + d];
            if (nb >= 0) {
                ++deg;
                const float4* nr = (const float4*)(x + (size_t)nb * D_IN);
                #pragma unroll
                for (int q = 0; q < 8; ++q) {
                    float4 t = nr[l * 8 + q];
                    agg[q].x += t.x; agg[q].y += t.y;
                    agg[q].z += t.z; agg[q].w += t.w;
                }
            }
        }
        const float inv = 1.0f / (float)deg;
        ushort* dst2 = sH + m * LDS_STRIDE + D_IN + l * 32;
        #pragma unroll
        for (int q = 0; q < 8; ++q) {
            ushort4 p = { (ushort)f2bf(agg[q].x*inv), (ushort)f2bf(agg[q].y*inv),
                          (ushort)f2bf(agg[q].z*inv), (ushort)f2bf(agg[q].w*inv) };
            *(ushort4*)(dst2 + q * 4) = p;
        }
    }
    __syncthreads();
    {
        const int wave = tid >> 6, lane = tid & 63;
        const int quad = lane >> 4, r16 = lane & 15;
        const int mt = wave & 1, nh = wave >> 1;
        f32x4 acc[8];
        #pragma unroll
        for (int j = 0; j < 8; ++j) {
            float bv = bias[(nh * 8 + j) * 16 + r16];
            acc[j] = (f32x4){bv, bv, bv, bv};
        }
        const ushort* arow = sH + (mt * 16 + r16) * LDS_STRIDE + quad * 8;
        #pragma unroll
        for (int ks = 0; ks < D_K / 32; ++ks) {
            bf16x8 a = *(const bf16x8*)(arow + ks * 32);
            #pragma unroll
            for (int j = 0; j < 8; ++j) {
                const int o = (nh * 8 + j) * 16 + r16;
                bf16x8 b = *(const bf16x8*)(Wb + (size_t)o * D_K + ks * 32 + quad * 8);
                acc[j] = __builtin_amdgcn_mfma_f32_16x16x32_bf16(a, b, acc[j], 0, 0, 0);
            }
        }
        #pragma unroll
        for (int j = 0; j < 8; ++j) {
            const int o = (nh * 8 + j) * 16 + r16;
            #pragma unroll
            for (int r = 0; r < 4; ++r) {
                const int row = node0 + mt * 16 + quad * 4 + r;
                out[(size_t)row * D_OUT + o] = acc[j][r];
            }
        }
    }
}

extern "C" void kernel_launch(void* const* d_in, const int* in_sizes, int n_in,
                              void* d_out, int out_size, void* d_ws, size_t ws_size,
                              hipStream_t stream) {
    const float* x    = (const float*)d_in[0];
    const int*   edge = (const int*)d_in[1];
    const float* W    = (const float*)d_in[2];
    const float* bias = (const float*)d_in[3];
    float* out = (float*)d_out;

    const size_t xb_bytes = (size_t)(N_NODES_C + 1) * D_IN * 2;   // 51,200,512
    const size_t wb_bytes = (size_t)D_OUT * D_K * 2;              // 262,144
    const int n = in_sizes[0] / D_IN;                             // 100000

    if (ws_size >= xb_bytes + wb_bytes) {
        ushort* Xb = (ushort*)d_ws;
        ushort* Wb = (ushort*)((char*)d_ws + xb_bytes);
        cast_all_kernel<<<12565, 256, 0, stream>>>(x, W, Xb, Wb);
        sage_bf16_kernel<<<n / BM, 512, 0, stream>>>(Xb, edge, Wb, bias, out);
    } else {
        ushort* Wb = (ushort*)d_ws;     // 256 KB
        cast_w_kernel<<<(D_OUT * D_K) / 1024, 256, 0, stream>>>(W, Wb);
        sage_fp32_kernel<<<n / 32, 256, 0, stream>>>(x, edge, Wb, bias, out);
    }
}